// Round 1
// 41.165 us; speedup vs baseline: 4.8944x; 4.8944x over previous
//
#include <hip/hip_runtime.h>

#define NQ 14
#define DIM (1 << NQ)       // 16384
#define NT 512
#define QD 6

typedef float2 c32;

__device__ __forceinline__ c32 cmul(c32 a, c32 b) {
  return make_float2(a.x * b.x - a.y * b.y, a.x * b.y + a.y * b.x);
}

// RY on local bit K of an NB-element register subcube (compile-time indices only)
template<int K, int NB>
__device__ __forceinline__ void apply_ry(c32* v, float c, float s) {
#pragma unroll
  for (int m = 0; m < NB / 2; ++m) {
    const int j0 = ((m >> K) << (K + 1)) | (m & ((1 << K) - 1));
    const int j1 = j0 | (1 << K);
    const c32 a0 = v[j0], a1 = v[j1];
    v[j0] = make_float2(c * a0.x - s * a1.x, c * a0.y - s * a1.y);
    v[j1] = make_float2(s * a0.x + c * a1.x, s * a0.y + c * a1.y);
  }
}

// <X> partial over local bit K: sum Re(conj(a0)*a1)
template<int K, int NB>
__device__ __forceinline__ float expv(const c32* v) {
  float acc = 0.f;
#pragma unroll
  for (int m = 0; m < NB / 2; ++m) {
    const int j0 = ((m >> K) << (K + 1)) | (m & ((1 << K) - 1));
    const int j1 = j0 | (1 << K);
    acc += v[j0].x * v[j1].x + v[j0].y * v[j1].y;
  }
  return acc;
}

__device__ __forceinline__ void wave_reduce_atomic(float val, float* dst) {
#pragma unroll
  for (int off = 32; off; off >>= 1) val += __shfl_down(val, off);
  if ((threadIdx.x & 63) == 0) atomicAdd(dst, val);
}

// per-wire 2-vector u = RY(q0) * RX(n) * RY(n) |0>
__device__ __forceinline__ void wire_u(float nz, float q0, c32& u0, c32& u1) {
  float sn, cn, sy, cy;
  __sincosf(0.5f * nz, &sn, &cn);
  __sincosf(0.5f * q0, &sy, &cy);
  const float cc = cn * cn, ss = sn * sn, cs = cn * sn;
  // g0 = (cc,-ss), g1 = (cs,-cs); u0 = cy*g0 - sy*g1; u1 = sy*g0 + cy*g1
  u0 = make_float2(cy * cc - sy * cs, sy * cs - cy * ss);
  u1 = make_float2(sy * cc + cy * cs, -sy * ss - cy * cs);
}

// ---- RY groups: A = bits 0-4 (wires 13..9), B = bits 5-9 (wires 8..4), C = bits 10-13 (wires 3..0)
__device__ __forceinline__ void ryA(c32* v, const float* __restrict__ qp, int l) {
  float c[5], s[5];
#pragma unroll
  for (int k = 0; k < 5; ++k) __sincosf(0.5f * qp[l * NQ + (13 - k)], &s[k], &c[k]);
  apply_ry<0, 32>(v, c[0], s[0]);
  apply_ry<1, 32>(v, c[1], s[1]);
  apply_ry<2, 32>(v, c[2], s[2]);
  apply_ry<3, 32>(v, c[3], s[3]);
  apply_ry<4, 32>(v, c[4], s[4]);
}
__device__ __forceinline__ void ryB(c32* v, const float* __restrict__ qp, int l) {
  float c[5], s[5];
#pragma unroll
  for (int k = 0; k < 5; ++k) __sincosf(0.5f * qp[l * NQ + (8 - k)], &s[k], &c[k]);
  apply_ry<0, 32>(v, c[0], s[0]);
  apply_ry<1, 32>(v, c[1], s[1]);
  apply_ry<2, 32>(v, c[2], s[2]);
  apply_ry<3, 32>(v, c[3], s[3]);
  apply_ry<4, 32>(v, c[4], s[4]);
}
__device__ __forceinline__ void ryC(c32 v[2][16], const float* __restrict__ qp, int l) {
  float c[4], s[4];
#pragma unroll
  for (int k = 0; k < 4; ++k) __sincosf(0.5f * qp[l * NQ + (3 - k)], &s[k], &c[k]);
#pragma unroll
  for (int r = 0; r < 2; ++r) {
    apply_ry<0, 16>(v[r], c[0], s[0]);
    apply_ry<1, 16>(v[r], c[1], s[1]);
    apply_ry<2, 16>(v[r], c[2], s[2]);
    apply_ry<3, 16>(v[r], c[3], s[3]);
  }
}

// ---- CZ ladder sign: parity(i & (i>>1)), split into thread-const ^ compile-time parts
__device__ __forceinline__ void czA(c32* v, int t) {   // i = (t<<5)|j
  const int pa = __popc(t & (t >> 1)) & 1;
  const int t0 = t & 1;
#pragma unroll
  for (int j = 0; j < 32; ++j) {
    const int sgn = pa ^ (__popc(j & (j >> 1)) & 1) ^ (((j >> 4) & 1) & t0);
    if (sgn) { v[j].x = -v[j].x; v[j].y = -v[j].y; }
  }
}
__device__ __forceinline__ void czB(c32* v, int t) {   // i = (hi<<10)|(j<<5)|lo
  const int lo = t & 31, hi = t >> 5;
  const int pb = (__popc(lo & (lo >> 1)) + __popc(hi & (hi >> 1))) & 1;
  const int lo4 = (lo >> 4) & 1, hi0 = hi & 1;
#pragma unroll
  for (int j = 0; j < 32; ++j) {
    const int sgn = pb ^ (__popc(j & (j >> 1)) & 1) ^ (lo4 & (j & 1)) ^ (((j >> 4) & 1) & hi0);
    if (sgn) { v[j].x = -v[j].x; v[j].y = -v[j].y; }
  }
}
__device__ __forceinline__ void czC(c32* v16, int o) { // i = (j<<10)|o
  const int pc = __popc(o & (o >> 1)) & 1;
  const int o9 = (o >> 9) & 1;
#pragma unroll
  for (int j = 0; j < 16; ++j) {
    const int sgn = pc ^ (__popc(j & (j >> 1)) & 1) ^ (o9 & (j & 1));
    if (sgn) { v16[j].x = -v16[j].x; v16[j].y = -v16[j].y; }
  }
}

// ---- sweeps. LDS layout swizzle: phys = i ^ ((i>>5)&31) — conflict-free in all 3 layouts.
template<int MODE>  // 0: RY(l); 1: RY(l)+CZ(l)+RY(l+1)
__device__ __forceinline__ void passA(c32* st, const float* __restrict__ qp, int t, int l) {
  c32 v[32];
  const int base = t << 5, x5 = t & 31;
#pragma unroll
  for (int j = 0; j < 32; ++j) v[j] = st[base | (j ^ x5)];
  ryA(v, qp, l);
  if (MODE == 1) { czA(v, t); ryA(v, qp, l + 1); }
#pragma unroll
  for (int j = 0; j < 32; ++j) st[base | (j ^ x5)] = v[j];
  __syncthreads();
}

template<int MODE>  // 0: RY; 1: RY+CZ+RY(l+1); 2: RY+CZ+exp partials (wires 8..4)
__device__ __forceinline__ void passB(c32* st, const float* __restrict__ qp, int t, int l,
                                      float* exps) {
  c32 v[32];
  const int bb = ((t >> 5) << 10) | (t & 31);
#pragma unroll
  for (int j = 0; j < 32; ++j) v[j] = st[bb ^ (j << 5) ^ j];
  ryB(v, qp, l);
  if (MODE == 1) { czB(v, t); ryB(v, qp, l + 1); }
  if (MODE == 2) {
    czB(v, t);
    wave_reduce_atomic(expv<0, 32>(v), &exps[8]);
    wave_reduce_atomic(expv<1, 32>(v), &exps[7]);
    wave_reduce_atomic(expv<2, 32>(v), &exps[6]);
    wave_reduce_atomic(expv<3, 32>(v), &exps[5]);
    wave_reduce_atomic(expv<4, 32>(v), &exps[4]);
  }
#pragma unroll
  for (int j = 0; j < 32; ++j) st[bb ^ (j << 5) ^ j] = v[j];
  __syncthreads();
}

template<int MODE>  // 0: RY(l); 1: RY(l)+CZ(l)+RY(l+1)
__device__ __forceinline__ void passC(c32* st, const float* __restrict__ qp, int t, int l) {
  c32 v[2][16];
#pragma unroll
  for (int r = 0; r < 2; ++r) {
    const int o = t + (r << 9);
    const int cb = o ^ (o >> 5);
#pragma unroll
    for (int j = 0; j < 16; ++j) v[r][j] = st[(j << 10) | cb];
  }
  ryC(v, qp, l);
  if (MODE == 1) {
#pragma unroll
    for (int r = 0; r < 2; ++r) czC(v[r], t + (r << 9));
    ryC(v, qp, l + 1);
  }
#pragma unroll
  for (int r = 0; r < 2; ++r) {
    const int o = t + (r << 9);
    const int cb = o ^ (o >> 5);
#pragma unroll
    for (int j = 0; j < 16; ++j) st[(j << 10) | cb] = v[r][j];
  }
  __syncthreads();
}

__global__ __launch_bounds__(NT, 2) void qsim_kernel(
    const float* __restrict__ noise, const float* __restrict__ qp,
    float* __restrict__ out) {
  __shared__ c32 st[DIM];       // 128 KiB, swizzled layout
  __shared__ float exps[NQ];
  const int b = blockIdx.x;
  const int t = threadIdx.x;
  if (t < NQ) exps[t] = 0.f;

  // ---- P0: product state = (RX*RY)(noise) + layer-0 RY, all on |0> -> pure registers ----
  c32 v[32];
  {
    c32 h = make_float2(1.f, 0.f);          // product over thread bits (global bits 5..13)
#pragma unroll
    for (int p = 5; p < 14; ++p) {
      c32 u0, u1;
      wire_u(noise[b * NQ + (13 - p)], qp[13 - p], u0, u1);
      const c32 pick = ((t >> (p - 5)) & 1) ? u1 : u0;
      h = cmul(h, pick);
    }
    {
      c32 u0, u1;
      wire_u(noise[b * NQ + 13], qp[13], u0, u1);
      v[0] = u0; v[1] = u1;
    }
#define BSTEP(P)                                                           \
    {                                                                      \
      c32 u0, u1;                                                          \
      wire_u(noise[b * NQ + (13 - (P))], qp[13 - (P)], u0, u1);            \
      _Pragma("unroll")                                                    \
      for (int j = 0; j < (1 << (P)); ++j) {                               \
        v[j | (1 << (P))] = cmul(v[j], u1);                                \
        v[j] = cmul(v[j], u0);                                             \
      }                                                                    \
    }
    BSTEP(1) BSTEP(2) BSTEP(3) BSTEP(4)
#undef BSTEP
#pragma unroll
    for (int j = 0; j < 32; ++j) v[j] = cmul(v[j], h);
  }
  czA(v, t);          // CZ of layer 0
  ryA(v, qp, 1);      // layer-1 A-group gates, still in registers
  {
    const int base = t << 5, x5 = t & 31;
#pragma unroll
    for (int j = 0; j < 32; ++j) st[base | (j ^ x5)] = v[j];
  }
  __syncthreads();

  // ---- rotated sweep schedule: 2 LDS round-trips per layer ----
  passB<0>(st, qp, t, 1, exps);
  passC<1>(st, qp, t, 1);       // + CZ1 + layer-2 C
  passA<0>(st, qp, t, 2);
  passB<1>(st, qp, t, 2, exps); // + CZ2 + layer-3 B
  passC<0>(st, qp, t, 3);
  passA<1>(st, qp, t, 3);       // + CZ3 + layer-4 A
  passB<0>(st, qp, t, 4, exps);
  passC<1>(st, qp, t, 4);       // + CZ4 + layer-5 C
  passA<0>(st, qp, t, 5);
  passB<2>(st, qp, t, 5, exps); // + CZ5 + <X> for wires 8..4, writes final state

  // ---- remaining expectations: A layout (wires 13..9), C layout (wires 3..0) ----
  {
    const int base = t << 5, x5 = t & 31;
#pragma unroll
    for (int j = 0; j < 32; ++j) v[j] = st[base | (j ^ x5)];
    wave_reduce_atomic(expv<0, 32>(v), &exps[13]);
    wave_reduce_atomic(expv<1, 32>(v), &exps[12]);
    wave_reduce_atomic(expv<2, 32>(v), &exps[11]);
    wave_reduce_atomic(expv<3, 32>(v), &exps[10]);
    wave_reduce_atomic(expv<4, 32>(v), &exps[9]);
  }
  {
    c32 w2[2][16];
#pragma unroll
    for (int r = 0; r < 2; ++r) {
      const int o = t + (r << 9);
      const int cb = o ^ (o >> 5);
#pragma unroll
      for (int j = 0; j < 16; ++j) w2[r][j] = st[(j << 10) | cb];
    }
    wave_reduce_atomic(expv<0, 16>(w2[0]) + expv<0, 16>(w2[1]), &exps[3]);
    wave_reduce_atomic(expv<1, 16>(w2[0]) + expv<1, 16>(w2[1]), &exps[2]);
    wave_reduce_atomic(expv<2, 16>(w2[0]) + expv<2, 16>(w2[1]), &exps[1]);
    wave_reduce_atomic(expv<3, 16>(w2[0]) + expv<3, 16>(w2[1]), &exps[0]);
  }
  __syncthreads();
  if (t < NQ) out[b * NQ + t] = 2.f * exps[t];
}

extern "C" void kernel_launch(void* const* d_in, const int* in_sizes, int n_in,
                              void* d_out, int out_size, void* d_ws, size_t ws_size,
                              hipStream_t stream) {
  const float* noise = (const float*)d_in[0];  // [64, 14]
  const float* qp    = (const float*)d_in[1];  // [6, 14]
  float* out = (float*)d_out;                  // [64, 14]
  qsim_kernel<<<64, NT, 0, stream>>>(noise, qp, out);
}